// Round 16
// baseline (190.282 us; speedup 1.0000x reference)
//
#include <hip/hip_runtime.h>
#include <hip/hip_bf16.h>
#include <stdint.h>

typedef int v4i __attribute__((ext_vector_type(4)));

#define AS_GLOBAL(p) ((const __attribute__((address_space(1))) void*)(p))
#define AS_LDS(p)    ((__attribute__((address_space(3))) void*)(p))

// ---------------- merged prepass: rows [0,M) = x - izp (+rowsum); rows [M, M+N) = w - 128
__global__ __launch_bounds__(256) void prep_kernel(const int* __restrict__ x,
                                                   const int* __restrict__ w,
                                                   const int* __restrict__ izp_p,
                                                   signed char* __restrict__ xs,
                                                   signed char* __restrict__ wsq,
                                                   int* __restrict__ rowsum, int M, int K) {
    int row = blockIdx.x;
    int n4 = K >> 2;
    if (row < M) {
        int izp = izp_p[0];
        const int4* xr = (const int4*)(x + (long)row * K);
        uint32_t* xo = (uint32_t*)(xs + (long)row * K);
        int sum = 0;
        for (int i = threadIdx.x; i < n4; i += 256) {
            int4 v = xr[i];
            int a0 = v.x - izp, a1 = v.y - izp, a2 = v.z - izp, a3 = v.w - izp;
            sum += a0 + a1 + a2 + a3;
            xo[i] = (uint32_t)(a0 & 0xFF) | ((uint32_t)(a1 & 0xFF) << 8) |
                    ((uint32_t)(a2 & 0xFF) << 16) | ((uint32_t)(a3 & 0xFF) << 24);
        }
        sum += __shfl_down(sum, 32);
        sum += __shfl_down(sum, 16);
        sum += __shfl_down(sum, 8);
        sum += __shfl_down(sum, 4);
        sum += __shfl_down(sum, 2);
        sum += __shfl_down(sum, 1);
        __shared__ int red[4];
        if ((threadIdx.x & 63) == 0) red[threadIdx.x >> 6] = sum;
        __syncthreads();
        if (threadIdx.x == 0) rowsum[row] = red[0] + red[1] + red[2] + red[3];
    } else {
        int wrow = row - M;
        const int4* wr = (const int4*)(w + (long)wrow * K);
        uint32_t* wo = (uint32_t*)(wsq + (long)wrow * K);
        for (int i = threadIdx.x; i < n4; i += 256) {
            int4 v = wr[i];
            int a0 = v.x - 128, a1 = v.y - 128, a2 = v.z - 128, a3 = v.w - 128;
            wo[i] = (uint32_t)(a0 & 0xFF) | ((uint32_t)(a1 & 0xFF) << 8) |
                    ((uint32_t)(a2 & 0xFF) << 16) | ((uint32_t)(a3 & 0xFF) << 24);
        }
    }
}

// ---------------- main GEMM: 256x256 tile, BK=128 int8, 16x16x64 MFMA ----------------
// 512 threads = 8 waves (2M x 4N); per-wave output 128x64 = acc[8][4] (16x16 frags)
// LDS 128 KiB: [buf:2][A:32KB | B:32KB]; st-swizzle LDS[row][c] = G[row][c^(row&7)]
// R16: m201's EXACT anatomy — 16-MFMA clusters (4 phases/K-tile), compiler-graded
//      lgkm waits, NO manual pins. The untested matrix cell: 16-clusters were only
//      ever run with entry pins (R2-R6); pin-free only on 32-clusters (R10/R15).
//      Short bursts double the boundaries where the SIMD's other wave's reads
//      interleave; graded waits let a wave enter its burst on first-operand-ready.
//      All reads consumed in-phase -> compiler waits retire them before each
//      phase's closing BAR; R2 stage-hazard table + VM4 accounting unchanged.

#define BAR  __builtin_amdgcn_s_barrier()
#define VM4  asm volatile("s_waitcnt vmcnt(4)" ::: "memory")
#define PRIO1 __builtin_amdgcn_s_setprio(1)
#define PRIO0 __builtin_amdgcn_s_setprio(0)

#define STAGE(gbase, opofs, half, buf, tile) do {                                     \
    int t_ = (tile); if (t_ >= NT) t_ -= NT;                                          \
    const signed char* src_ = (gbase) + (long)((half) * 128) * K + (long)t_ * 128;    \
    signed char* dst_ = ldsw + (buf) * 65536 + (opofs) + (half) * 16384;              \
    __builtin_amdgcn_global_load_lds(AS_GLOBAL(src_), AS_LDS(dst_), 16, 0, 0);        \
    __builtin_amdgcn_global_load_lds(AS_GLOBAL(src_ + 64L * K), AS_LDS(dst_ + 8192), 16, 0, 0); \
  } while (0)

#define READ_A(buf, mi) do {                                                          \
    af[mi][0] = *(const v4i*)(lds + (buf) * 65536 + aoff0 + (mi) * 2048);             \
    af[mi][1] = *(const v4i*)(lds + (buf) * 65536 + aoff1 + (mi) * 2048); } while (0)
#define READ_B(buf, ni) do {                                                          \
    bf[ni][0] = *(const v4i*)(lds + (buf) * 65536 + boff0 + (ni) * 2048);             \
    bf[ni][1] = *(const v4i*)(lds + (buf) * 65536 + boff1 + (ni) * 2048); } while (0)

#define MFMA_1(mi, ni, ks)                                                             \
    acc[mi][ni] = __builtin_amdgcn_mfma_i32_16x16x64_i8(af[mi][ks], bf[ni][ks], acc[mi][ni], 0, 0, 0);

// quad (mb..mb+3, nb..nb+1), ks-outer: 8 independent MFMAs, then their 8 partners.
#define MFMAQ(mb, nb) do {                                                             \
    MFMA_1(mb + 0, nb + 0, 0) MFMA_1(mb + 0, nb + 1, 0)                                \
    MFMA_1(mb + 1, nb + 0, 0) MFMA_1(mb + 1, nb + 1, 0)                                \
    MFMA_1(mb + 2, nb + 0, 0) MFMA_1(mb + 2, nb + 1, 0)                                \
    MFMA_1(mb + 3, nb + 0, 0) MFMA_1(mb + 3, nb + 1, 0)                                \
    MFMA_1(mb + 0, nb + 0, 1) MFMA_1(mb + 0, nb + 1, 1)                                \
    MFMA_1(mb + 1, nb + 0, 1) MFMA_1(mb + 1, nb + 1, 1)                                \
    MFMA_1(mb + 2, nb + 0, 1) MFMA_1(mb + 2, nb + 1, 1)                                \
    MFMA_1(mb + 3, nb + 0, 1) MFMA_1(mb + 3, nb + 1, 1) } while (0)

// One K-tile from buf b; stages tile tA's A-halves into buf b^1 (ph1,ph2) and
// tile tB's B-halves into buf b (ph3,ph4). Reads 12/4/8/0, each consumed by its
// own phase's quadrant (compiler-graded waits retire them before the closing BAR).
#define KTILE(b, tA, tB) do {                                                          \
    /* ph1: 12 reads, quad (m0,n0) */                                                  \
    READ_A(b, 0); READ_A(b, 1); READ_B(b, 0); READ_B(b, 1);                            \
    READ_A(b, 2); READ_A(b, 3);                                                        \
    STAGE(gA, 0, 0, (b) ^ 1, tA);                                                      \
    BAR;                                                                               \
    PRIO1; MFMAQ(0, 0); PRIO0;                                                         \
    BAR;                                                                               \
    /* ph2: 4 reads, quad (m0,n1) */                                                   \
    READ_B(b, 2); READ_B(b, 3);                                                        \
    STAGE(gA, 0, 1, (b) ^ 1, tA);                                                      \
    BAR;                                                                               \
    PRIO1; MFMAQ(0, 2); PRIO0;                                                         \
    BAR;                                                                               \
    /* ph3: 8 reads, quad (m1,n0) */                                                   \
    READ_A(b, 4); READ_A(b, 5); READ_A(b, 6); READ_A(b, 7);                            \
    STAGE(gB, 32768, 0, (b), tB);                                                      \
    BAR;                                                                               \
    PRIO1; MFMAQ(4, 0); PRIO0;                                                         \
    BAR;                                                                               \
    /* ph4: no reads, quad (m1,n1) */                                                  \
    STAGE(gB, 32768, 1, (b), tB);                                                      \
    BAR;                                                                               \
    PRIO1; MFMAQ(4, 2); PRIO0; VM4;                                                    \
    BAR;                                                                               \
  } while (0)

__global__ __launch_bounds__(512, 2) void gemm_i8_8ph(
    const signed char* __restrict__ A,   // xs [M,K]
    const signed char* __restrict__ B,   // ws [N,K]
    const int* __restrict__ rowsum, const float* __restrict__ wscale,
    const int* __restrict__ wzp, const float* __restrict__ bias,
    const float* __restrict__ iscale, float* __restrict__ C,
    int M, int N, int K) {
  __shared__ signed char lds[131072];
  const int tid = threadIdx.x;
  const int w = tid >> 6, l = tid & 63;
  const int wm = w >> 2, wn = w & 3;
  const int fr = l & 15, fq = l >> 4;

  int nwg = gridDim.x, bid = blockIdx.x;
  if ((nwg & 7) == 0) { int cpx = nwg >> 3; bid = (bid & 7) * cpx + (bid >> 3); }
  const int ntiles = N >> 8;
  const int mt = bid / ntiles, nt = bid - mt * ntiles;
  const long brow = (long)mt << 8, bcol = (long)nt << 8;

  const int NT = K >> 7;      // K-tiles of 128 bytes
  const int NI = NT >> 1;     // 2 K-tiles per iteration

  // staging lane constants (unchanged from R2)
  const int srow = w * 8 + (l >> 3);
  const int schunk = ((l & 7) ^ (l >> 3)) << 4;
  const signed char* gA = A + (brow + srow) * (long)K + schunk;
  const signed char* gB = B + (bcol + srow) * (long)K + schunk;
  signed char* ldsw = lds + w * 1024;   // wave-uniform LDS dest component

  // fragment read offsets (swizzled chunk = (ks*4+fq) ^ (fr&7))
  const int axor = fr & 7;
  const int aoff0 = (wm * 128 + fr) * 128 + ((fq ^ axor) << 4);
  const int aoff1 = (wm * 128 + fr) * 128 + (((4 + fq) ^ axor) << 4);
  const int boff0 = 32768 + (wn * 64 + fr) * 128 + ((fq ^ axor) << 4);
  const int boff1 = 32768 + (wn * 64 + fr) * 128 + (((4 + fq) ^ axor) << 4);

  v4i acc[8][4] = {};
  v4i af[8][2], bf[4][2];

  // prologue: tile0 -> buf0 (B,A), tile1 B -> buf1; wait first 8, keep 4 in flight
  STAGE(gB, 32768, 0, 0, 0); STAGE(gB, 32768, 1, 0, 0);
  STAGE(gA, 0, 0, 0, 0);     STAGE(gA, 0, 1, 0, 0);
  STAGE(gB, 32768, 0, 1, 1); STAGE(gB, 32768, 1, 1, 1);
  VM4; BAR;

  for (int i = 0; i < NI; ++i) {
    const int t1 = 2 * i + 1, t2 = 2 * i + 2, t3 = 2 * i + 3;
    KTILE(0, t1, t2);   // K-tile 2i   from buf0
    KTILE(1, t2, t3);   // K-tile 2i+1 from buf1
  }

  // epilogue: out = (acc + (128 - wzp[n]) * rowsum[m]) * (iscale * wscale[n]) + bias[n]
  const float is = iscale[0];
  int rs[8][4];
#pragma unroll
  for (int mi = 0; mi < 8; ++mi)
#pragma unroll
    for (int j = 0; j < 4; ++j)
      rs[mi][j] = rowsum[(int)brow + wm * 128 + mi * 16 + fq * 4 + j];
#pragma unroll
  for (int ni = 0; ni < 4; ++ni) {
    const int col = (int)bcol + wn * 64 + ni * 16 + fr;
    const float sc = is * wscale[col];
    const int zpc = 128 - wzp[col];
    const float bi = bias[col];
#pragma unroll
    for (int mi = 0; mi < 8; ++mi) {
      const int row0 = (int)brow + wm * 128 + mi * 16 + fq * 4;
#pragma unroll
      for (int j = 0; j < 4; ++j) {
        const int v = acc[mi][ni][j] + zpc * rs[mi][j];
        C[(long)(row0 + j) * N + col] = (float)v * sc + bi;
      }
    }
  }
}

extern "C" void kernel_launch(void* const* d_in, const int* in_sizes, int n_in,
                              void* d_out, int out_size, void* d_ws, size_t ws_size,
                              hipStream_t stream) {
    const int* x_q = (const int*)d_in[0];
    const int* w_q = (const int*)d_in[1];
    const float* wscale = (const float*)d_in[2];
    const int* wzp = (const int*)d_in[3];
    const float* bias = (const float*)d_in[4];
    const float* iscale = (const float*)d_in[5];
    const int* izp = (const int*)d_in[6];

    int N = in_sizes[2];            // weight_scale has N elements
    int K = in_sizes[1] / N;        // weight is [N, K]
    int M = in_sizes[0] / K;        // x is [M, K]

    signed char* xs = (signed char*)d_ws;
    signed char* wsq = xs + (size_t)M * K;
    int* rowsum = (int*)(wsq + (size_t)N * K);

    prep_kernel<<<M + N, 256, 0, stream>>>(x_q, w_q, izp, xs, wsq, rowsum, M, K);

    int grid = (M / 256) * (N / 256);
    gemm_i8_8ph<<<grid, 512, 0, stream>>>(xs, wsq, rowsum, wscale, wzp, bias, iscale,
                                          (float*)d_out, M, N, K);
}

// Round 17
// 186.212 us; speedup vs baseline: 1.0219x; 1.0219x over previous
//
#include <hip/hip_runtime.h>
#include <hip/hip_bf16.h>
#include <stdint.h>

typedef int v4i __attribute__((ext_vector_type(4)));

#define AS_GLOBAL(p) ((const __attribute__((address_space(1))) void*)(p))
#define AS_LDS(p)    ((__attribute__((address_space(3))) void*)(p))

// ---------------- merged prepass: rows [0,M) = x - izp (+rowsum); rows [M, M+N) = w - 128
__global__ __launch_bounds__(256) void prep_kernel(const int* __restrict__ x,
                                                   const int* __restrict__ w,
                                                   const int* __restrict__ izp_p,
                                                   signed char* __restrict__ xs,
                                                   signed char* __restrict__ wsq,
                                                   int* __restrict__ rowsum, int M, int K) {
    int row = blockIdx.x;
    int n4 = K >> 2;
    if (row < M) {
        int izp = izp_p[0];
        const int4* xr = (const int4*)(x + (long)row * K);
        uint32_t* xo = (uint32_t*)(xs + (long)row * K);
        int sum = 0;
        for (int i = threadIdx.x; i < n4; i += 256) {
            int4 v = xr[i];
            int a0 = v.x - izp, a1 = v.y - izp, a2 = v.z - izp, a3 = v.w - izp;
            sum += a0 + a1 + a2 + a3;
            xo[i] = (uint32_t)(a0 & 0xFF) | ((uint32_t)(a1 & 0xFF) << 8) |
                    ((uint32_t)(a2 & 0xFF) << 16) | ((uint32_t)(a3 & 0xFF) << 24);
        }
        sum += __shfl_down(sum, 32);
        sum += __shfl_down(sum, 16);
        sum += __shfl_down(sum, 8);
        sum += __shfl_down(sum, 4);
        sum += __shfl_down(sum, 2);
        sum += __shfl_down(sum, 1);
        __shared__ int red[4];
        if ((threadIdx.x & 63) == 0) red[threadIdx.x >> 6] = sum;
        __syncthreads();
        if (threadIdx.x == 0) rowsum[row] = red[0] + red[1] + red[2] + red[3];
    } else {
        int wrow = row - M;
        const int4* wr = (const int4*)(w + (long)wrow * K);
        uint32_t* wo = (uint32_t*)(wsq + (long)wrow * K);
        for (int i = threadIdx.x; i < n4; i += 256) {
            int4 v = wr[i];
            int a0 = v.x - 128, a1 = v.y - 128, a2 = v.z - 128, a3 = v.w - 128;
            wo[i] = (uint32_t)(a0 & 0xFF) | ((uint32_t)(a1 & 0xFF) << 8) |
                    ((uint32_t)(a2 & 0xFF) << 16) | ((uint32_t)(a3 & 0xFF) << 24);
        }
    }
}

// ---------------- main GEMM: 256x256 tile, BK=128 int8, 16x16x64 MFMA ----------------
// FINAL (R15 revert = best measured): pins-free 2-superphase double-buffered loop.
// Ledger R2-R16 (12 structurally distinct probes: schedules, graded/counted waits,
// barrier density, MFMA shape, occupancy incl. independent 4-wave blocks, 4-deep
// never-drain pipeline, B-in-registers) all land 5250-5500 cyc/K-tile =
// LDS-service (~2800) + MFMA (~2613) SUM — the two demands do not overlap for
// i8 MFMA on gfx950 regardless of program structure (R12 rules out program-order).
// Both demands are geometry-minimal; this is the practical floor for this op.

#define BAR  __builtin_amdgcn_s_barrier()
#define VM4  asm volatile("s_waitcnt vmcnt(4)" ::: "memory")
#define PRIO1 __builtin_amdgcn_s_setprio(1)
#define PRIO0 __builtin_amdgcn_s_setprio(0)

#define STAGE(gbase, opofs, half, buf, tile) do {                                     \
    int t_ = (tile); if (t_ >= NT) t_ -= NT;                                          \
    const signed char* src_ = (gbase) + (long)((half) * 128) * K + (long)t_ * 128;    \
    signed char* dst_ = ldsw + (buf) * 65536 + (opofs) + (half) * 16384;              \
    __builtin_amdgcn_global_load_lds(AS_GLOBAL(src_), AS_LDS(dst_), 16, 0, 0);        \
    __builtin_amdgcn_global_load_lds(AS_GLOBAL(src_ + 64L * K), AS_LDS(dst_ + 8192), 16, 0, 0); \
  } while (0)

// afs[s][ks] holds A-frag for acc row (mb + s); storage reused across phases.
#define READ_AS(buf, s, mi) do {                                                      \
    afs[s][0] = *(const v4i*)(lds + (buf) * 65536 + aoff0 + (mi) * 2048);             \
    afs[s][1] = *(const v4i*)(lds + (buf) * 65536 + aoff1 + (mi) * 2048); } while (0)
#define READ_B(buf, ni) do {                                                          \
    bf[ni][0] = *(const v4i*)(lds + (buf) * 65536 + boff0 + (ni) * 2048);             \
    bf[ni][1] = *(const v4i*)(lds + (buf) * 65536 + boff1 + (ni) * 2048); } while (0)

#define M1(s, mi, ni, ks)                                                              \
    acc[mi][ni] = __builtin_amdgcn_mfma_i32_16x16x64_i8(afs[s][ks], bf[ni][ks], acc[mi][ni], 0, 0, 0);

// 32 MFMA for acc rows mb..mb+3 x all 4 ni: ks-outer (16 independent, then 16).
#define MFMA32(mb) do {                                                                \
    M1(0, mb + 0, 0, 0) M1(0, mb + 0, 1, 0) M1(1, mb + 1, 0, 0) M1(1, mb + 1, 1, 0)   \
    M1(2, mb + 2, 0, 0) M1(2, mb + 2, 1, 0) M1(3, mb + 3, 0, 0) M1(3, mb + 3, 1, 0)   \
    M1(0, mb + 0, 2, 0) M1(0, mb + 0, 3, 0) M1(1, mb + 1, 2, 0) M1(1, mb + 1, 3, 0)   \
    M1(2, mb + 2, 2, 0) M1(2, mb + 2, 3, 0) M1(3, mb + 3, 2, 0) M1(3, mb + 3, 3, 0)   \
    M1(0, mb + 0, 0, 1) M1(0, mb + 0, 1, 1) M1(1, mb + 1, 0, 1) M1(1, mb + 1, 1, 1)   \
    M1(2, mb + 2, 0, 1) M1(2, mb + 2, 1, 1) M1(3, mb + 3, 0, 1) M1(3, mb + 3, 1, 1)   \
    M1(0, mb + 0, 2, 1) M1(0, mb + 0, 3, 1) M1(1, mb + 1, 2, 1) M1(1, mb + 1, 3, 1)   \
    M1(2, mb + 2, 2, 1) M1(2, mb + 2, 3, 1) M1(3, mb + 3, 2, 1) M1(3, mb + 3, 3, 1)   \
  } while (0)

#define KTILE(b, tA, tB) do {                                                          \
    /* phase A: 16 reads (af0-3 both ks, bf0-3 both ks), A-stages, 32 MFMA */          \
    READ_AS(b, 0, 0); READ_AS(b, 1, 1); READ_AS(b, 2, 2); READ_AS(b, 3, 3);            \
    READ_B(b, 0); READ_B(b, 1); READ_B(b, 2); READ_B(b, 3);                            \
    STAGE(gA, 0, 0, (b) ^ 1, tA); STAGE(gA, 0, 1, (b) ^ 1, tA);                        \
    PRIO1; MFMA32(0); PRIO0;                                                           \
    BAR;                                                                               \
    /* phase B: 8 reads (af4-7 into same storage), B-stages, 32 MFMA */                \
    READ_AS(b, 0, 4); READ_AS(b, 1, 5); READ_AS(b, 2, 6); READ_AS(b, 3, 7);            \
    STAGE(gB, 32768, 0, (b), tB); STAGE(gB, 32768, 1, (b), tB);                        \
    PRIO1; MFMA32(4); PRIO0;                                                           \
    VM4; BAR;                                                                          \
  } while (0)

__global__ __launch_bounds__(512, 2) void gemm_i8_8ph(
    const signed char* __restrict__ A,   // xs [M,K]
    const signed char* __restrict__ B,   // ws [N,K]
    const int* __restrict__ rowsum, const float* __restrict__ wscale,
    const int* __restrict__ wzp, const float* __restrict__ bias,
    const float* __restrict__ iscale, float* __restrict__ C,
    int M, int N, int K) {
  __shared__ signed char lds[131072];
  const int tid = threadIdx.x;
  const int w = tid >> 6, l = tid & 63;
  const int wm = w >> 2, wn = w & 3;
  const int fr = l & 15, fq = l >> 4;

  int nwg = gridDim.x, bid = blockIdx.x;
  if ((nwg & 7) == 0) { int cpx = nwg >> 3; bid = (bid & 7) * cpx + (bid >> 3); }
  const int ntiles = N >> 8;
  const int mt = bid / ntiles, nt = bid - mt * ntiles;
  const long brow = (long)mt << 8, bcol = (long)nt << 8;

  const int NT = K >> 7;      // K-tiles of 128 bytes
  const int NI = NT >> 1;     // 2 K-tiles per iteration

  // staging lane constants (R2 scheme, proven 0-conflict)
  const int srow = w * 8 + (l >> 3);
  const int schunk = ((l & 7) ^ (l >> 3)) << 4;
  const signed char* gA = A + (brow + srow) * (long)K + schunk;
  const signed char* gB = B + (bcol + srow) * (long)K + schunk;
  signed char* ldsw = lds + w * 1024;   // wave-uniform LDS dest component

  // fragment read offsets (swizzled chunk = (ks*4+fq) ^ (fr&7))
  const int axor = fr & 7;
  const int aoff0 = (wm * 128 + fr) * 128 + ((fq ^ axor) << 4);
  const int aoff1 = (wm * 128 + fr) * 128 + (((4 + fq) ^ axor) << 4);
  const int boff0 = 32768 + (wn * 64 + fr) * 128 + ((fq ^ axor) << 4);
  const int boff1 = 32768 + (wn * 64 + fr) * 128 + (((4 + fq) ^ axor) << 4);

  v4i acc[8][4] = {};
  v4i afs[4][2], bf[4][2];   // 16 live v4i fragments max

  // prologue: tile0 -> buf0 (B,A), tile1 B -> buf1; wait first 8, keep 4 in flight
  STAGE(gB, 32768, 0, 0, 0); STAGE(gB, 32768, 1, 0, 0);
  STAGE(gA, 0, 0, 0, 0);     STAGE(gA, 0, 1, 0, 0);
  STAGE(gB, 32768, 0, 1, 1); STAGE(gB, 32768, 1, 1, 1);
  VM4; BAR;

  for (int i = 0; i < NI; ++i) {
    const int t1 = 2 * i + 1, t2 = 2 * i + 2, t3 = 2 * i + 3;
    KTILE(0, t1, t2);   // K-tile 2i   from buf0
    KTILE(1, t2, t3);   // K-tile 2i+1 from buf1
  }

  // epilogue: out = (acc + (128 - wzp[n]) * rowsum[m]) * (iscale * wscale[n]) + bias[n]
  const float is = iscale[0];
  int rs[8][4];
#pragma unroll
  for (int mi = 0; mi < 8; ++mi)
#pragma unroll
    for (int j = 0; j < 4; ++j)
      rs[mi][j] = rowsum[(int)brow + wm * 128 + mi * 16 + fq * 4 + j];
#pragma unroll
  for (int ni = 0; ni < 4; ++ni) {
    const int col = (int)bcol + wn * 64 + ni * 16 + fr;
    const float sc = is * wscale[col];
    const int zpc = 128 - wzp[col];
    const float bi = bias[col];
#pragma unroll
    for (int mi = 0; mi < 8; ++mi) {
      const int row0 = (int)brow + wm * 128 + mi * 16 + fq * 4;
#pragma unroll
      for (int j = 0; j < 4; ++j) {
        const int v = acc[mi][ni][j] + zpc * rs[mi][j];
        C[(long)(row0 + j) * N + col] = (float)v * sc + bi;
      }
    }
  }
}

extern "C" void kernel_launch(void* const* d_in, const int* in_sizes, int n_in,
                              void* d_out, int out_size, void* d_ws, size_t ws_size,
                              hipStream_t stream) {
    const int* x_q = (const int*)d_in[0];
    const int* w_q = (const int*)d_in[1];
    const float* wscale = (const float*)d_in[2];
    const int* wzp = (const int*)d_in[3];
    const float* bias = (const float*)d_in[4];
    const float* iscale = (const float*)d_in[5];
    const int* izp = (const int*)d_in[6];

    int N = in_sizes[2];            // weight_scale has N elements
    int K = in_sizes[1] / N;        // weight is [N, K]
    int M = in_sizes[0] / K;        // x is [M, K]

    signed char* xs = (signed char*)d_ws;
    signed char* wsq = xs + (size_t)M * K;
    int* rowsum = (int*)(wsq + (size_t)N * K);

    prep_kernel<<<M + N, 256, 0, stream>>>(x_q, w_q, izp, xs, wsq, rowsum, M, K);

    int grid = (M / 256) * (N / 256);
    gemm_i8_8ph<<<grid, 512, 0, stream>>>(xs, wsq, rowsum, wscale, wzp, bias, iscale,
                                          (float*)d_out, M, N, K);
}